// Round 1
// baseline (1920.424 us; speedup 1.0000x reference)
//
#include <hip/hip_runtime.h>
#include <hip/hip_bf16.h>

#define N_NODES 100000
#define N_EDGES 1600000
#define CH 64

// ---------------- CSR build ----------------

__global__ void k_hist(const int* __restrict__ dst, int* __restrict__ cnt, int E) {
    int i = blockIdx.x * blockDim.x + threadIdx.x;
    if (i < E) atomicAdd(&cnt[dst[i]], 1);
}

// blocks of 1024 threads, 1024 elements each: exclusive scan within block,
// block totals to bsum.
__global__ __launch_bounds__(1024) void k_scanA(const int* __restrict__ cnt, int N,
                                                int* __restrict__ rowp, int* __restrict__ bsum) {
    __shared__ int s[1024];
    int t = threadIdx.x;
    int g = blockIdx.x * 1024 + t;
    int v = (g < N) ? cnt[g] : 0;
    s[t] = v;
    __syncthreads();
    for (int off = 1; off < 1024; off <<= 1) {
        int x = (t >= off) ? s[t - off] : 0;
        __syncthreads();
        s[t] += x;
        __syncthreads();
    }
    if (g < N) rowp[g] = s[t] - v;          // exclusive within block
    if (t == 1023) bsum[blockIdx.x] = s[1023];
}

__global__ void k_scanB(int* __restrict__ bsum, int nb) {
    if (blockIdx.x == 0 && threadIdx.x == 0) {
        int acc = 0;
        for (int i = 0; i < nb; ++i) { int v = bsum[i]; bsum[i] = acc; acc += v; }
    }
}

__global__ void k_scanC(int* __restrict__ rowp, const int* __restrict__ cnt,
                        const int* __restrict__ bsum, int* __restrict__ cursor,
                        float* __restrict__ dinv, int N) {
    int g = blockIdx.x * blockDim.x + threadIdx.x;
    if (g < N) {
        int r = rowp[g] + bsum[g >> 10];
        rowp[g]   = r;
        cursor[g] = r;
        int d = cnt[g];
        dinv[g] = 1.0f / (float)(d > 1 ? d : 1);
    }
}

__global__ void k_fill(const int* __restrict__ src, const int* __restrict__ dst,
                       int* __restrict__ cursor, int* __restrict__ col, int E) {
    int i = blockIdx.x * blockDim.x + threadIdx.x;
    if (i < E) {
        int p = atomicAdd(&cursor[dst[i]], 1);
        col[p] = src[i];
    }
}

// ---------------- fused SAGE layer ----------------
// one wave per node; lane = channel.
// out[n][o] = bl[o] + sum_c agg[n][c]*Wl[o][c] + sum_c h[n][c]*Wr[o][c]
__global__ __launch_bounds__(256) void k_sage(const float* __restrict__ in,
                                              const int* __restrict__ rowp,
                                              const int* __restrict__ cnt,
                                              const float* __restrict__ dinv,
                                              const int* __restrict__ col,
                                              const float* __restrict__ Wl,
                                              const float* __restrict__ bl,
                                              const float* __restrict__ Wr,
                                              float* __restrict__ out,
                                              int relu, int N) {
    // transposed weights in LDS: sW[c*64+o]  (read sW[c*64+lane]: bank = lane%32, conflict-free)
    __shared__ float sWl[CH * CH];
    __shared__ float sWr[CH * CH];
    __shared__ float sBl[CH];
    int tid = threadIdx.x;
    for (int i = tid; i < CH * CH; i += 256) {
        int o = i >> 6, c = i & 63;
        sWl[c * CH + o] = Wl[i];
        sWr[c * CH + o] = Wr[i];
    }
    if (tid < CH) sBl[tid] = bl[tid];
    __syncthreads();

    int wave = tid >> 6, lane = tid & 63;
    int n = blockIdx.x * 4 + wave;
    if (n >= N) return;

    int start = rowp[n];
    int deg   = cnt[n];
    float acc = 0.f;
    for (int e = 0; e < deg; ++e) {
        int s = col[start + e];
        acc += in[s * CH + lane];
    }
    acc *= dinv[n];
    float hv = in[n * CH + lane];

    float o = sBl[lane];
#pragma unroll
    for (int c = 0; c < CH; ++c) {
        float a = __shfl(acc, c, 64);
        float h = __shfl(hv, c, 64);
        o += a * sWl[c * CH + lane] + h * sWr[c * CH + lane];
    }
    if (relu) o = fmaxf(o, 0.f);
    out[n * CH + lane] = o;
}

// ---------------- launch ----------------

extern "C" void kernel_launch(void* const* d_in, const int* in_sizes, int n_in,
                              void* d_out, int out_size, void* d_ws, size_t ws_size,
                              hipStream_t stream) {
    const float* x   = (const float*)d_in[0];
    const int*   ei  = (const int*)d_in[1];
    const int E = in_sizes[1] / 2;
    const int N = in_sizes[0] / CH;
    const int* src = ei;
    const int* dst = ei + E;

    const float* Wl[3] = { (const float*)d_in[2], (const float*)d_in[5], (const float*)d_in[8] };
    const float* bl[3] = { (const float*)d_in[3], (const float*)d_in[6], (const float*)d_in[9] };
    const float* Wr[3] = { (const float*)d_in[4], (const float*)d_in[7], (const float*)d_in[10] };

    char* ws = (char*)d_ws;
    size_t off = 0;
    auto take = [&](size_t bytes) { char* p = ws + off; off += (bytes + 255) & ~(size_t)255; return p; };
    int*   cnt    = (int*)  take((size_t)N * 4);
    int*   rowp   = (int*)  take((size_t)(N + 1) * 4);
    int*   cursor = (int*)  take((size_t)N * 4);
    float* dinv   = (float*)take((size_t)N * 4);
    int*   bsum   = (int*)  take(4096);
    int*   col    = (int*)  take((size_t)E * 4);
    float* buf0   = (float*)take((size_t)N * CH * 4);
    float* buf1   = (float*)take((size_t)N * CH * 4);
    float* outp   = (float*)d_out;

    hipMemsetAsync(cnt, 0, (size_t)N * 4, stream);

    int tb = 256;
    k_hist<<<(E + tb - 1) / tb, tb, 0, stream>>>(dst, cnt, E);

    int nb = (N + 1023) / 1024;
    k_scanA<<<nb, 1024, 0, stream>>>(cnt, N, rowp, bsum);
    k_scanB<<<1, 64, 0, stream>>>(bsum, nb);
    k_scanC<<<(N + tb - 1) / tb, tb, 0, stream>>>(rowp, cnt, bsum, cursor, dinv, N);
    k_fill<<<(E + tb - 1) / tb, tb, 0, stream>>>(src, dst, cursor, col, E);

    int blocks = (N + 3) / 4;  // 4 nodes (waves) per block
    k_sage<<<blocks, 256, 0, stream>>>(x,    rowp, cnt, dinv, col, Wl[0], bl[0], Wr[0], buf0, 1, N);
    k_sage<<<blocks, 256, 0, stream>>>(buf0, rowp, cnt, dinv, col, Wl[1], bl[1], Wr[1], buf1, 1, N);
    k_sage<<<blocks, 256, 0, stream>>>(buf1, rowp, cnt, dinv, col, Wl[2], bl[2], Wr[2], outp, 0, N);
}

// Round 3
// 724.062 us; speedup vs baseline: 2.6523x; 2.6523x over previous
//
#include <hip/hip_runtime.h>
#include <hip/hip_bf16.h>

#define N_NODES 100000
#define N_EDGES 1600000
#define CH 64
#define WPAD 65   // padded LDS leading dim: bank-conflict-free staging + reads

// ---------------- CSR build ----------------

__global__ void k_hist(const int* __restrict__ dst, int* __restrict__ cnt, int E) {
    int i = blockIdx.x * blockDim.x + threadIdx.x;
    if (i < E) atomicAdd(&cnt[dst[i]], 1);
}

__global__ __launch_bounds__(1024) void k_scanA(const int* __restrict__ cnt, int N,
                                                int* __restrict__ rowp, int* __restrict__ bsum) {
    __shared__ int s[1024];
    int t = threadIdx.x;
    int g = blockIdx.x * 1024 + t;
    int v = (g < N) ? cnt[g] : 0;
    s[t] = v;
    __syncthreads();
    for (int off = 1; off < 1024; off <<= 1) {
        int x = (t >= off) ? s[t - off] : 0;
        __syncthreads();
        s[t] += x;
        __syncthreads();
    }
    if (g < N) rowp[g] = s[t] - v;          // exclusive within block
    if (t == 1023) bsum[blockIdx.x] = s[1023];
}

__global__ void k_scanB(int* __restrict__ bsum, int nb) {
    if (blockIdx.x == 0 && threadIdx.x == 0) {
        int acc = 0;
        for (int i = 0; i < nb; ++i) { int v = bsum[i]; bsum[i] = acc; acc += v; }
    }
}

__global__ void k_scanC(int* __restrict__ rowp, const int* __restrict__ cnt,
                        const int* __restrict__ bsum, int* __restrict__ cursor,
                        float* __restrict__ dinv, int N) {
    int g = blockIdx.x * blockDim.x + threadIdx.x;
    if (g < N) {
        int r = rowp[g] + bsum[g >> 10];
        rowp[g]   = r;
        cursor[g] = r;
        int d = cnt[g];
        dinv[g] = 1.0f / (float)(d > 1 ? d : 1);
    }
}

__global__ void k_fill(const int* __restrict__ src, const int* __restrict__ dst,
                       int* __restrict__ cursor, int* __restrict__ col, int E) {
    int i = blockIdx.x * blockDim.x + threadIdx.x;
    if (i < E) {
        int p = atomicAdd(&cursor[dst[i]], 1);
        col[p] = src[i];
    }
}

// ---------------- fused SAGE layer ----------------
// one wave per node; lane = channel. grid-stride over node groups so the
// weight staging (32 KB LDS) amortizes over ~12 groups per block.
__global__ __launch_bounds__(256) void k_sage(const float* __restrict__ in,
                                              const int* __restrict__ rowp,
                                              const int* __restrict__ cnt,
                                              const float* __restrict__ dinv,
                                              const int* __restrict__ col,
                                              const float* __restrict__ Wl,
                                              const float* __restrict__ bl,
                                              const float* __restrict__ Wr,
                                              float* __restrict__ out,
                                              int relu, int N) {
    // sW[c*WPAD+o] = W[o*64+c]. Staging: consecutive threads read consecutive
    // global (coalesced) and write addr-stride 65 words -> bank stride 1 (no
    // conflict). Inner read sW[c*WPAD+lane]: bank (c+lane)%32 -> 2-way (free).
    __shared__ float sWl[CH * WPAD];
    __shared__ float sWr[CH * WPAD];
    __shared__ float sBl[CH];
    int tid = threadIdx.x;
    for (int i = tid; i < CH * CH; i += 256) {
        int o = i >> 6, c = i & 63;
        sWl[c * WPAD + o] = Wl[i];
        sWr[c * WPAD + o] = Wr[i];
    }
    if (tid < CH) sBl[tid] = bl[tid];
    __syncthreads();

    int wave = tid >> 6, lane = tid & 63;
    int ngroups = (N + 3) >> 2;

    for (int g = blockIdx.x; g < ngroups; g += gridDim.x) {
        int n = g * 4 + wave;
        if (n >= N) continue;

        int start = rowp[n];
        int deg   = cnt[n];

        // gather-mean: unroll by 4 with independent accumulators so 4 loads
        // are in flight (breaks the col->feature latency chain)
        float a0 = 0.f, a1 = 0.f, a2 = 0.f, a3 = 0.f;
        int e = 0;
        for (; e + 4 <= deg; e += 4) {
            int s0 = col[start + e];
            int s1 = col[start + e + 1];
            int s2 = col[start + e + 2];
            int s3 = col[start + e + 3];
            a0 += in[s0 * CH + lane];
            a1 += in[s1 * CH + lane];
            a2 += in[s2 * CH + lane];
            a3 += in[s3 * CH + lane];
        }
        for (; e < deg; ++e) a0 += in[col[start + e] * CH + lane];
        float acc = ((a0 + a1) + (a2 + a3)) * dinv[n];
        float hv  = in[n * CH + lane];

        // out[n][lane] = bl[lane] + sum_c acc[c]*Wl[lane][c] + hv[c]*Wr[lane][c]
        // broadcast acc[c], hv[c] via readlane (SGPR) -> no LDS-pipe bpermute
        float o = sBl[lane];
#pragma unroll
        for (int c = 0; c < CH; ++c) {
            float a = __uint_as_float(__builtin_amdgcn_readlane(__float_as_uint(acc), c));
            float h = __uint_as_float(__builtin_amdgcn_readlane(__float_as_uint(hv),  c));
            o += a * sWl[c * WPAD + lane];
            o += h * sWr[c * WPAD + lane];
        }
        if (relu) o = fmaxf(o, 0.f);
        out[n * CH + lane] = o;
    }
}

// ---------------- launch ----------------

extern "C" void kernel_launch(void* const* d_in, const int* in_sizes, int n_in,
                              void* d_out, int out_size, void* d_ws, size_t ws_size,
                              hipStream_t stream) {
    const float* x   = (const float*)d_in[0];
    const int*   ei  = (const int*)d_in[1];
    const int E = in_sizes[1] / 2;
    const int N = in_sizes[0] / CH;
    const int* src = ei;
    const int* dst = ei + E;

    const float* Wl[3] = { (const float*)d_in[2], (const float*)d_in[5], (const float*)d_in[8] };
    const float* bl[3] = { (const float*)d_in[3], (const float*)d_in[6], (const float*)d_in[9] };
    const float* Wr[3] = { (const float*)d_in[4], (const float*)d_in[7], (const float*)d_in[10] };

    char* ws = (char*)d_ws;
    size_t off = 0;
    auto take = [&](size_t bytes) { char* p = ws + off; off += (bytes + 255) & ~(size_t)255; return p; };
    int*   cnt    = (int*)  take((size_t)N * 4);
    int*   rowp   = (int*)  take((size_t)(N + 1) * 4);
    int*   cursor = (int*)  take((size_t)N * 4);
    float* dinv   = (float*)take((size_t)N * 4);
    int*   bsum   = (int*)  take(4096);
    int*   col    = (int*)  take((size_t)E * 4);
    float* buf0   = (float*)take((size_t)N * CH * 4);
    float* buf1   = (float*)take((size_t)N * CH * 4);
    float* outp   = (float*)d_out;

    hipMemsetAsync(cnt, 0, (size_t)N * 4, stream);

    int tb = 256;
    k_hist<<<(E + tb - 1) / tb, tb, 0, stream>>>(dst, cnt, E);

    int nb = (N + 1023) / 1024;
    k_scanA<<<nb, 1024, 0, stream>>>(cnt, N, rowp, bsum);
    k_scanB<<<1, 64, 0, stream>>>(bsum, nb);
    k_scanC<<<(N + tb - 1) / tb, tb, 0, stream>>>(rowp, cnt, bsum, cursor, dinv, N);
    k_fill<<<(E + tb - 1) / tb, tb, 0, stream>>>(src, dst, cursor, col, E);

    int blocks = 2048;  // grid-stride; LDS 33.5KB -> 4 blocks/CU resident
    k_sage<<<blocks, 256, 0, stream>>>(x,    rowp, cnt, dinv, col, Wl[0], bl[0], Wr[0], buf0, 1, N);
    k_sage<<<blocks, 256, 0, stream>>>(buf0, rowp, cnt, dinv, col, Wl[1], bl[1], Wr[1], buf1, 1, N);
    k_sage<<<blocks, 256, 0, stream>>>(buf1, rowp, cnt, dinv, col, Wl[2], bl[2], Wr[2], outp, 0, N);
}

// Round 5
// 646.925 us; speedup vs baseline: 2.9685x; 1.1192x over previous
//
#include <hip/hip_runtime.h>
#include <hip/hip_bf16.h>

#define N_NODES 100000
#define N_EDGES 1600000
#define CH 64

// ---------------- helpers ----------------

__device__ __forceinline__ unsigned short f2bf(float f) {
    unsigned int u = __float_as_uint(f);
    u += 0x7FFF + ((u >> 16) & 1);          // round-to-nearest-even
    return (unsigned short)(u >> 16);
}
__device__ __forceinline__ float bf2f(unsigned short b) {
    return __uint_as_float(((unsigned int)b) << 16);
}

// ---------------- CSR build ----------------

__global__ void k_hist(const int* __restrict__ dst, int* __restrict__ cnt, int E) {
    int i = blockIdx.x * blockDim.x + threadIdx.x;
    int E4 = E >> 2;
    if (i < E4) {
        int4 d = ((const int4*)dst)[i];
        atomicAdd(&cnt[d.x], 1);
        atomicAdd(&cnt[d.y], 1);
        atomicAdd(&cnt[d.z], 1);
        atomicAdd(&cnt[d.w], 1);
    }
    if (i == 0) for (int e = E4 * 4; e < E; ++e) atomicAdd(&cnt[dst[e]], 1);
}

__global__ __launch_bounds__(1024) void k_scanA(const int* __restrict__ cnt, int N,
                                                int* __restrict__ rowp, int* __restrict__ bsum) {
    __shared__ int s[1024];
    int t = threadIdx.x;
    int g = blockIdx.x * 1024 + t;
    int v = (g < N) ? cnt[g] : 0;
    s[t] = v;
    __syncthreads();
    for (int off = 1; off < 1024; off <<= 1) {
        int x = (t >= off) ? s[t - off] : 0;
        __syncthreads();
        s[t] += x;
        __syncthreads();
    }
    if (g < N) rowp[g] = s[t] - v;          // exclusive within block
    if (t == 1023) bsum[blockIdx.x] = s[1023];
}

// parallel exclusive scan of block totals (nb <= 1024)
__global__ __launch_bounds__(1024) void k_scanB(int* __restrict__ bsum, int nb) {
    __shared__ int s[1024];
    int t = threadIdx.x;
    int v = (t < nb) ? bsum[t] : 0;
    s[t] = v;
    __syncthreads();
    for (int off = 1; off < 1024; off <<= 1) {
        int x = (t >= off) ? s[t - off] : 0;
        __syncthreads();
        s[t] += x;
        __syncthreads();
    }
    if (t < nb) bsum[t] = s[t] - v;         // exclusive
}

__global__ void k_scanC(int* __restrict__ rowp, const int* __restrict__ cnt,
                        const int* __restrict__ bsum, int* __restrict__ cursor,
                        float* __restrict__ dinv, int N) {
    int g = blockIdx.x * blockDim.x + threadIdx.x;
    if (g < N) {
        int r = rowp[g] + bsum[g >> 10];
        rowp[g]   = r;
        cursor[g] = r;
        int d = cnt[g];
        dinv[g] = 1.0f / (float)(d > 1 ? d : 1);
    }
}

__global__ void k_fill(const int* __restrict__ src, const int* __restrict__ dst,
                       int* __restrict__ cursor, int* __restrict__ col, int E) {
    int i = blockIdx.x * blockDim.x + threadIdx.x;
    int E4 = E >> 2;
    if (i < E4) {
        int4 s = ((const int4*)src)[i];
        int4 d = ((const int4*)dst)[i];
        col[atomicAdd(&cursor[d.x], 1)] = s.x;
        col[atomicAdd(&cursor[d.y], 1)] = s.y;
        col[atomicAdd(&cursor[d.z], 1)] = s.z;
        col[atomicAdd(&cursor[d.w], 1)] = s.w;
    }
    if (i == 0) for (int e = E4 * 4; e < E; ++e)
        col[atomicAdd(&cursor[dst[e]], 1)] = src[e];
}

// ---------------- dense transform ----------------
// T[n][o] = sum_c h[n][c]*Wl[o][c]   (bf16, consumed only via mean -> error ~2.5e-4)
// S[n][o] = bl[o] + sum_c h[n][c]*Wr[o][c]
// lane = o. Weight rows live in registers (128 VGPR); h[c] broadcast via readlane.
__global__ __launch_bounds__(256) void k_transform(const float* __restrict__ h,
                                                   const float* __restrict__ Wl,
                                                   const float* __restrict__ bl,
                                                   const float* __restrict__ Wr,
                                                   unsigned short* __restrict__ T,
                                                   float* __restrict__ S, int N) {
    int lane = threadIdx.x & 63;
    float wl[CH], wr[CH];
    const float4* Wl4 = (const float4*)(Wl + lane * CH);
    const float4* Wr4 = (const float4*)(Wr + lane * CH);
#pragma unroll
    for (int q = 0; q < CH / 4; ++q) {
        float4 a = Wl4[q];
        wl[4 * q] = a.x; wl[4 * q + 1] = a.y; wl[4 * q + 2] = a.z; wl[4 * q + 3] = a.w;
        float4 b = Wr4[q];
        wr[4 * q] = b.x; wr[4 * q + 1] = b.y; wr[4 * q + 2] = b.z; wr[4 * q + 3] = b.w;
    }
    float bias = bl[lane];

    int wid    = (blockIdx.x * blockDim.x + threadIdx.x) >> 6;
    int nwaves = (gridDim.x * blockDim.x) >> 6;
    for (int n = wid; n < N; n += nwaves) {
        float hv = h[n * CH + lane];
        float ol = 0.f, orr = 0.f;
#pragma unroll
        for (int c = 0; c < CH; ++c) {
            float hc = __uint_as_float(__builtin_amdgcn_readlane(__float_as_uint(hv), c));
            ol  += hc * wl[c];
            orr += hc * wr[c];
        }
        T[n * CH + lane] = f2bf(ol);
        S[n * CH + lane] = orr + bias;
    }
}

// ---------------- gather ----------------
// out[n][lane] = relu?( S[n][lane] + dinv[n] * sum_e T[col[e]][lane] )
// one wave per node; gathered row = 64 lanes x 2B = 128B = one cache line.
__global__ __launch_bounds__(256) void k_gather(const unsigned short* __restrict__ T,
                                                const float* __restrict__ S,
                                                const int* __restrict__ rowp,
                                                const int* __restrict__ cnt,
                                                const float* __restrict__ dinv,
                                                const int* __restrict__ col,
                                                float* __restrict__ out,
                                                int relu, int N) {
    int wave = threadIdx.x >> 6, lane = threadIdx.x & 63;
    int n = blockIdx.x * 4 + wave;
    if (n >= N) return;

    int start = rowp[n];
    int deg   = cnt[n];

    float a0 = 0.f, a1 = 0.f, a2 = 0.f, a3 = 0.f;
    int e = 0;
    for (; e + 4 <= deg; e += 4) {
        int s0 = col[start + e];
        int s1 = col[start + e + 1];
        int s2 = col[start + e + 2];
        int s3 = col[start + e + 3];
        a0 += bf2f(T[s0 * CH + lane]);
        a1 += bf2f(T[s1 * CH + lane]);
        a2 += bf2f(T[s2 * CH + lane]);
        a3 += bf2f(T[s3 * CH + lane]);
    }
    for (; e < deg; ++e) a0 += bf2f(T[col[start + e] * CH + lane]);

    float o = S[n * CH + lane] + ((a0 + a1) + (a2 + a3)) * dinv[n];
    if (relu) o = fmaxf(o, 0.f);
    out[n * CH + lane] = o;
}

// ---------------- launch ----------------

extern "C" void kernel_launch(void* const* d_in, const int* in_sizes, int n_in,
                              void* d_out, int out_size, void* d_ws, size_t ws_size,
                              hipStream_t stream) {
    const float* x   = (const float*)d_in[0];
    const int*   ei  = (const int*)d_in[1];
    const int E = in_sizes[1] / 2;
    const int N = in_sizes[0] / CH;
    const int* src = ei;
    const int* dst = ei + E;

    const float* Wl[3] = { (const float*)d_in[2], (const float*)d_in[5], (const float*)d_in[8] };
    const float* bl[3] = { (const float*)d_in[3], (const float*)d_in[6], (const float*)d_in[9] };
    const float* Wr[3] = { (const float*)d_in[4], (const float*)d_in[7], (const float*)d_in[10] };

    char* ws = (char*)d_ws;
    size_t off = 0;
    auto take = [&](size_t bytes) { char* p = ws + off; off += (bytes + 255) & ~(size_t)255; return p; };
    int*            cnt    = (int*)           take((size_t)N * 4);
    int*            rowp   = (int*)           take((size_t)(N + 1) * 4);
    int*            cursor = (int*)           take((size_t)N * 4);
    float*          dinv   = (float*)         take((size_t)N * 4);
    int*            bsum   = (int*)           take(4096);
    int*            col    = (int*)           take((size_t)E * 4);
    unsigned short* T      = (unsigned short*)take((size_t)N * CH * 2);
    float*          S      = (float*)         take((size_t)N * CH * 4);
    float*          buf0   = (float*)         take((size_t)N * CH * 4);
    float*          outp   = (float*)d_out;

    hipMemsetAsync(cnt, 0, (size_t)N * 4, stream);

    int tb = 256;
    int E4 = E >> 2;
    k_hist<<<(E4 + tb - 1) / tb, tb, 0, stream>>>(dst, cnt, E);

    int nb = (N + 1023) / 1024;
    k_scanA<<<nb, 1024, 0, stream>>>(cnt, N, rowp, bsum);
    k_scanB<<<1, 1024, 0, stream>>>(bsum, nb);
    k_scanC<<<(N + tb - 1) / tb, tb, 0, stream>>>(rowp, cnt, bsum, cursor, dinv, N);
    k_fill<<<(E4 + tb - 1) / tb, tb, 0, stream>>>(src, dst, cursor, col, E);

    int gblocks = (N + 3) / 4;
    // layer 0
    k_transform<<<1024, 256, 0, stream>>>(x, Wl[0], bl[0], Wr[0], T, S, N);
    k_gather<<<gblocks, 256, 0, stream>>>(T, S, rowp, cnt, dinv, col, buf0, 1, N);
    // layer 1 (gather may overwrite buf0: stream-ordered after transform read)
    k_transform<<<1024, 256, 0, stream>>>(buf0, Wl[1], bl[1], Wr[1], T, S, N);
    k_gather<<<gblocks, 256, 0, stream>>>(T, S, rowp, cnt, dinv, col, buf0, 1, N);
    // layer 2
    k_transform<<<1024, 256, 0, stream>>>(buf0, Wl[2], bl[2], Wr[2], T, S, N);
    k_gather<<<gblocks, 256, 0, stream>>>(T, S, rowp, cnt, dinv, col, outp, 0, N);
}

// Round 6
// 581.939 us; speedup vs baseline: 3.3000x; 1.1117x over previous
//
#include <hip/hip_runtime.h>
#include <hip/hip_bf16.h>

#define N_NODES 100000
#define N_EDGES 1600000
#define CH 64
#define NPASS 8   // k_fill dst-range passes: col window/pass ~0.8MB -> L2-resident

// ---------------- helpers ----------------

__device__ __forceinline__ unsigned short f2bf(float f) {
    unsigned int u = __float_as_uint(f);
    u += 0x7FFF + ((u >> 16) & 1);          // round-to-nearest-even
    return (unsigned short)(u >> 16);
}
__device__ __forceinline__ float bf2f(unsigned short b) {
    return __uint_as_float(((unsigned int)b) << 16);
}

// ---------------- CSR build ----------------

__global__ void k_hist(const int* __restrict__ dst, int* __restrict__ cnt, int E) {
    int i = blockIdx.x * blockDim.x + threadIdx.x;
    int E4 = E >> 2;
    if (i < E4) {
        int4 d = ((const int4*)dst)[i];
        atomicAdd(&cnt[d.x], 1);
        atomicAdd(&cnt[d.y], 1);
        atomicAdd(&cnt[d.z], 1);
        atomicAdd(&cnt[d.w], 1);
    }
    if (i == 0) for (int e = E4 * 4; e < E; ++e) atomicAdd(&cnt[dst[e]], 1);
}

__global__ __launch_bounds__(1024) void k_scanA(const int* __restrict__ cnt, int N,
                                                int* __restrict__ rowp, int* __restrict__ bsum) {
    __shared__ int s[1024];
    int t = threadIdx.x;
    int g = blockIdx.x * 1024 + t;
    int v = (g < N) ? cnt[g] : 0;
    s[t] = v;
    __syncthreads();
    for (int off = 1; off < 1024; off <<= 1) {
        int x = (t >= off) ? s[t - off] : 0;
        __syncthreads();
        s[t] += x;
        __syncthreads();
    }
    if (g < N) rowp[g] = s[t] - v;          // exclusive within block
    if (t == 1023) bsum[blockIdx.x] = s[1023];
}

// parallel exclusive scan of block totals (nb <= 1024)
__global__ __launch_bounds__(1024) void k_scanB(int* __restrict__ bsum, int nb) {
    __shared__ int s[1024];
    int t = threadIdx.x;
    int v = (t < nb) ? bsum[t] : 0;
    s[t] = v;
    __syncthreads();
    for (int off = 1; off < 1024; off <<= 1) {
        int x = (t >= off) ? s[t - off] : 0;
        __syncthreads();
        s[t] += x;
        __syncthreads();
    }
    if (t < nb) bsum[t] = s[t] - v;         // exclusive
}

__global__ void k_scanC(int* __restrict__ rowp, const int* __restrict__ cnt,
                        const int* __restrict__ bsum, int* __restrict__ cursor,
                        float* __restrict__ dinv, int N) {
    int g = blockIdx.x * blockDim.x + threadIdx.x;
    if (g < N) {
        int r = rowp[g] + bsum[g >> 10];
        rowp[g]   = r;
        cursor[g] = r;
        int d = cnt[g];
        dinv[g] = 1.0f / (float)(d > 1 ? d : 1);
    }
}

// multi-pass fill: pass p only handles dst in [p*span,(p+1)*span) so the col
// write-window (~0.8MB) stays L2-resident -> each line written back once, not
// once per dword. All blocks resident -> passes proceed in near-lockstep and
// the edge chunks are L2-hits after pass 0.
__global__ __launch_bounds__(256) void k_fill(const int* __restrict__ src,
                                              const int* __restrict__ dst,
                                              int* __restrict__ cursor,
                                              int* __restrict__ col, int E, int N) {
    int E4 = E >> 2;
    int tid = blockIdx.x * blockDim.x + threadIdx.x;
    int nth = gridDim.x * blockDim.x;
    int span = (N + NPASS - 1) / NPASS;
    for (int p = 0; p < NPASS; ++p) {
        int lo = p * span, hi = lo + span;
        for (int i = tid; i < E4; i += nth) {
            int4 d = ((const int4*)dst)[i];
            int4 s = ((const int4*)src)[i];
            if (d.x >= lo && d.x < hi) col[atomicAdd(&cursor[d.x], 1)] = s.x;
            if (d.y >= lo && d.y < hi) col[atomicAdd(&cursor[d.y], 1)] = s.y;
            if (d.z >= lo && d.z < hi) col[atomicAdd(&cursor[d.z], 1)] = s.z;
            if (d.w >= lo && d.w < hi) col[atomicAdd(&cursor[d.w], 1)] = s.w;
        }
    }
    if (tid == 0) for (int e = E4 * 4; e < E; ++e)
        col[atomicAdd(&cursor[dst[e]], 1)] = src[e];
}

// ---------------- dense transform ----------------
// T[n][o] = sum_c h[n][c]*Wl[o][c]   (bf16, consumed only via mean -> error ~2.5e-4)
// S[n][o] = bl[o] + sum_c h[n][c]*Wr[o][c]
// lane = o. Weight rows live in registers (128 VGPR); h[c] broadcast via readlane.
__global__ __launch_bounds__(256) void k_transform(const float* __restrict__ h,
                                                   const float* __restrict__ Wl,
                                                   const float* __restrict__ bl,
                                                   const float* __restrict__ Wr,
                                                   unsigned short* __restrict__ T,
                                                   float* __restrict__ S, int N) {
    int lane = threadIdx.x & 63;
    float wl[CH], wr[CH];
    const float4* Wl4 = (const float4*)(Wl + lane * CH);
    const float4* Wr4 = (const float4*)(Wr + lane * CH);
#pragma unroll
    for (int q = 0; q < CH / 4; ++q) {
        float4 a = Wl4[q];
        wl[4 * q] = a.x; wl[4 * q + 1] = a.y; wl[4 * q + 2] = a.z; wl[4 * q + 3] = a.w;
        float4 b = Wr4[q];
        wr[4 * q] = b.x; wr[4 * q + 1] = b.y; wr[4 * q + 2] = b.z; wr[4 * q + 3] = b.w;
    }
    float bias = bl[lane];

    int wid    = (blockIdx.x * blockDim.x + threadIdx.x) >> 6;
    int nwaves = (gridDim.x * blockDim.x) >> 6;
    for (int n = wid; n < N; n += nwaves) {
        float hv = h[n * CH + lane];
        float ol = 0.f, orr = 0.f;
#pragma unroll
        for (int c = 0; c < CH; ++c) {
            float hc = __uint_as_float(__builtin_amdgcn_readlane(__float_as_uint(hv), c));
            ol  += hc * wl[c];
            orr += hc * wr[c];
        }
        T[n * CH + lane] = f2bf(ol);
        S[n * CH + lane] = orr + bias;
    }
}

// ---------------- gather ----------------
// out[n][c] = relu?( S[n][c] + dinv[n] * sum_e T[col[e]][c] )
// one wave per node; 32 lanes x uint (2 bf16) per row -> 2 edges per
// wave-iteration, unrolled x4 = 8 edge-rows in flight.
__global__ __launch_bounds__(256) void k_gather(const unsigned short* __restrict__ T,
                                                const float* __restrict__ S,
                                                const int* __restrict__ rowp,
                                                const int* __restrict__ cnt,
                                                const float* __restrict__ dinv,
                                                const int* __restrict__ col,
                                                float* __restrict__ out,
                                                int relu, int N) {
    int wave = threadIdx.x >> 6, lane = threadIdx.x & 63;
    int half = lane >> 5, li = lane & 31;
    int n = blockIdx.x * 4 + wave;
    if (n >= N) return;

    int start = rowp[n];
    int deg   = cnt[n];
    const int* cp = col + start;

    float a0 = 0.f, a1 = 0.f, b0 = 0.f, b1 = 0.f;
    float c0 = 0.f, c1 = 0.f, d0 = 0.f, d1 = 0.f;
    int e = 0;
    for (; e + 8 <= deg; e += 8) {
        int s0 = cp[e + 0 + half];
        int s1 = cp[e + 2 + half];
        int s2 = cp[e + 4 + half];
        int s3 = cp[e + 6 + half];
        unsigned u0 = *(const unsigned*)(T + (size_t)s0 * CH + 2 * li);
        unsigned u1 = *(const unsigned*)(T + (size_t)s1 * CH + 2 * li);
        unsigned u2 = *(const unsigned*)(T + (size_t)s2 * CH + 2 * li);
        unsigned u3 = *(const unsigned*)(T + (size_t)s3 * CH + 2 * li);
        a0 += bf2f((unsigned short)u0); a1 += bf2f((unsigned short)(u0 >> 16));
        b0 += bf2f((unsigned short)u1); b1 += bf2f((unsigned short)(u1 >> 16));
        c0 += bf2f((unsigned short)u2); c1 += bf2f((unsigned short)(u2 >> 16));
        d0 += bf2f((unsigned short)u3); d1 += bf2f((unsigned short)(u3 >> 16));
    }
    for (; e < deg; e += 2) {
        if (e + half < deg) {
            int s = cp[e + half];
            unsigned u = *(const unsigned*)(T + (size_t)s * CH + 2 * li);
            a0 += bf2f((unsigned short)u); a1 += bf2f((unsigned short)(u >> 16));
        }
    }
    float r0 = (a0 + b0) + (c0 + d0);
    float r1 = (a1 + b1) + (c1 + d1);
    // combine the two 32-lane halves (each summed a disjoint edge subset)
    r0 += __shfl(r0, lane ^ 32, 64);
    r1 += __shfl(r1, lane ^ 32, 64);

    if (half == 0) {
        float dv = dinv[n];
        float2 sv = *(const float2*)(S + (size_t)n * CH + 2 * li);
        float o0 = sv.x + r0 * dv;
        float o1 = sv.y + r1 * dv;
        if (relu) { o0 = fmaxf(o0, 0.f); o1 = fmaxf(o1, 0.f); }
        *(float2*)(out + (size_t)n * CH + 2 * li) = make_float2(o0, o1);
    }
}

// ---------------- launch ----------------

extern "C" void kernel_launch(void* const* d_in, const int* in_sizes, int n_in,
                              void* d_out, int out_size, void* d_ws, size_t ws_size,
                              hipStream_t stream) {
    const float* x   = (const float*)d_in[0];
    const int*   ei  = (const int*)d_in[1];
    const int E = in_sizes[1] / 2;
    const int N = in_sizes[0] / CH;
    const int* src = ei;
    const int* dst = ei + E;

    const float* Wl[3] = { (const float*)d_in[2], (const float*)d_in[5], (const float*)d_in[8] };
    const float* bl[3] = { (const float*)d_in[3], (const float*)d_in[6], (const float*)d_in[9] };
    const float* Wr[3] = { (const float*)d_in[4], (const float*)d_in[7], (const float*)d_in[10] };

    char* ws = (char*)d_ws;
    size_t off = 0;
    auto take = [&](size_t bytes) { char* p = ws + off; off += (bytes + 255) & ~(size_t)255; return p; };
    int*            cnt    = (int*)           take((size_t)N * 4);
    int*            rowp   = (int*)           take((size_t)(N + 1) * 4);
    int*            cursor = (int*)           take((size_t)N * 4);
    float*          dinv   = (float*)         take((size_t)N * 4);
    int*            bsum   = (int*)           take(4096);
    int*            col    = (int*)           take((size_t)E * 4);
    unsigned short* T      = (unsigned short*)take((size_t)N * CH * 2);
    float*          S      = (float*)         take((size_t)N * CH * 4);
    float*          buf0   = (float*)         take((size_t)N * CH * 4);
    float*          outp   = (float*)d_out;

    hipMemsetAsync(cnt, 0, (size_t)N * 4, stream);

    int tb = 256;
    int E4 = E >> 2;
    k_hist<<<(E4 + tb - 1) / tb, tb, 0, stream>>>(dst, cnt, E);

    int nb = (N + 1023) / 1024;
    k_scanA<<<nb, 1024, 0, stream>>>(cnt, N, rowp, bsum);
    k_scanB<<<1, 1024, 0, stream>>>(bsum, nb);
    k_scanC<<<(N + tb - 1) / tb, tb, 0, stream>>>(rowp, cnt, bsum, cursor, dinv, N);

    // one int4 per thread per pass; ~1563 blocks all resident -> lockstep passes
    int fblocks = (E4 + tb - 1) / tb;
    k_fill<<<fblocks, tb, 0, stream>>>(src, dst, cursor, col, E, N);

    int gblocks = (N + 3) / 4;
    // layer 0
    k_transform<<<1024, 256, 0, stream>>>(x, Wl[0], bl[0], Wr[0], T, S, N);
    k_gather<<<gblocks, 256, 0, stream>>>(T, S, rowp, cnt, dinv, col, buf0, 1, N);
    // layer 1
    k_transform<<<1024, 256, 0, stream>>>(buf0, Wl[1], bl[1], Wr[1], T, S, N);
    k_gather<<<gblocks, 256, 0, stream>>>(T, S, rowp, cnt, dinv, col, buf0, 1, N);
    // layer 2
    k_transform<<<1024, 256, 0, stream>>>(buf0, Wl[2], bl[2], Wr[2], T, S, N);
    k_gather<<<gblocks, 256, 0, stream>>>(T, S, rowp, cnt, dinv, col, outp, 0, N);
}

// Round 11
// 535.343 us; speedup vs baseline: 3.5873x; 1.0870x over previous
//
#include <hip/hip_runtime.h>
#include <hip/hip_bf16.h>

#define N_NODES 100000
#define N_EDGES 1600000
#define CH 64
#define NRANGE 8   // dst-range groups; blockIdx&7 ~ XCD id under round-robin dispatch.
                   // Correctness never depends on placement (each range is covered by
                   // its block group); placement only decides L2 locality.

// ---------------- helpers ----------------

__device__ __forceinline__ unsigned short f2bf(float f) {
    unsigned int u = __float_as_uint(f);
    u += 0x7FFF + ((u >> 16) & 1);          // round-to-nearest-even
    return (unsigned short)(u >> 16);
}
__device__ __forceinline__ float bf2f(unsigned short b) {
    return __uint_as_float(((unsigned int)b) << 16);
}

// ---------------- CSR build ----------------

// XCD-partitioned histogram: group r touches only cnt[lo..hi) -> each cnt line
// is atomicked from one XCD only (no cross-XCD line bouncing / writeback dup).
__global__ __launch_bounds__(256) void k_hist(const int* __restrict__ dst,
                                              int* __restrict__ cnt, int E, int N) {
    int E4 = E >> 2;
    int r    = blockIdx.x & (NRANGE - 1);
    int gtid = (blockIdx.x >> 3) * blockDim.x + threadIdx.x;
    int gnth = (gridDim.x >> 3) * blockDim.x;
    int span = (N + NRANGE - 1) / NRANGE;
    int lo = r * span, hi = lo + span;
    for (int i = gtid; i < E4; i += gnth) {
        int4 d = ((const int4*)dst)[i];
        if (d.x >= lo && d.x < hi) atomicAdd(&cnt[d.x], 1);
        if (d.y >= lo && d.y < hi) atomicAdd(&cnt[d.y], 1);
        if (d.z >= lo && d.z < hi) atomicAdd(&cnt[d.z], 1);
        if (d.w >= lo && d.w < hi) atomicAdd(&cnt[d.w], 1);
    }
    if (blockIdx.x == 0 && threadIdx.x == 0)
        for (int e = E4 * 4; e < E; ++e) atomicAdd(&cnt[dst[e]], 1);
}

__global__ __launch_bounds__(1024) void k_scanA(const int* __restrict__ cnt, int N,
                                                int* __restrict__ rowp, int* __restrict__ bsum) {
    __shared__ int s[1024];
    int t = threadIdx.x;
    int g = blockIdx.x * 1024 + t;
    int v = (g < N) ? cnt[g] : 0;
    s[t] = v;
    __syncthreads();
    for (int off = 1; off < 1024; off <<= 1) {
        int x = (t >= off) ? s[t - off] : 0;
        __syncthreads();
        s[t] += x;
        __syncthreads();
    }
    if (g < N) rowp[g] = s[t] - v;          // exclusive within block
    if (t == 1023) bsum[blockIdx.x] = s[1023];
}

// parallel exclusive scan of block totals (nb <= 1024)
__global__ __launch_bounds__(1024) void k_scanB(int* __restrict__ bsum, int nb) {
    __shared__ int s[1024];
    int t = threadIdx.x;
    int v = (t < nb) ? bsum[t] : 0;
    s[t] = v;
    __syncthreads();
    for (int off = 1; off < 1024; off <<= 1) {
        int x = (t >= off) ? s[t - off] : 0;
        __syncthreads();
        s[t] += x;
        __syncthreads();
    }
    if (t < nb) bsum[t] = s[t] - v;         // exclusive
}

__global__ void k_scanC(int* __restrict__ rowp, const int* __restrict__ cnt,
                        const int* __restrict__ bsum, int* __restrict__ cursor,
                        float* __restrict__ dinv, int N) {
    int g = blockIdx.x * blockDim.x + threadIdx.x;
    if (g < N) {
        int r = rowp[g] + bsum[g >> 10];
        rowp[g]   = r;
        cursor[g] = r;
        int d = cnt[g];
        dinv[g] = 1.0f / (float)(d > 1 ? d : 1);
    }
}

// XCD-partitioned fill: group r writes only col[rowp[lo]..rowp[hi]) (~0.8MB)
// -> window L2-resident on ONE XCD, every col line dirtied in one L2 and
// written back once (round 6 showed per-XCD partial-dirty lines caused ~14x
// write amplification when all XCDs wrote the same window).
__global__ __launch_bounds__(256) void k_fill(const int* __restrict__ src,
                                              const int* __restrict__ dst,
                                              int* __restrict__ cursor,
                                              int* __restrict__ col, int E, int N) {
    int E4 = E >> 2;
    int r    = blockIdx.x & (NRANGE - 1);
    int gtid = (blockIdx.x >> 3) * blockDim.x + threadIdx.x;
    int gnth = (gridDim.x >> 3) * blockDim.x;
    int span = (N + NRANGE - 1) / NRANGE;
    int lo = r * span, hi = lo + span;
    for (int i = gtid; i < E4; i += gnth) {
        int4 d = ((const int4*)dst)[i];
        int4 s = ((const int4*)src)[i];
        if (d.x >= lo && d.x < hi) col[atomicAdd(&cursor[d.x], 1)] = s.x;
        if (d.y >= lo && d.y < hi) col[atomicAdd(&cursor[d.y], 1)] = s.y;
        if (d.z >= lo && d.z < hi) col[atomicAdd(&cursor[d.z], 1)] = s.z;
        if (d.w >= lo && d.w < hi) col[atomicAdd(&cursor[d.w], 1)] = s.w;
    }
    if (blockIdx.x == 0 && threadIdx.x == 0)
        for (int e = E4 * 4; e < E; ++e)
            col[atomicAdd(&cursor[dst[e]], 1)] = src[e];
}

// ---------------- dense transform ----------------
// T[n][o] = sum_c h[n][c]*Wl[o][c]   (bf16, consumed only via mean -> error ~2.5e-4)
// S[n][o] = bl[o] + sum_c h[n][c]*Wr[o][c]
// lane = o. Weight rows live in registers (128 VGPR); h[c] broadcast via readlane.
__global__ __launch_bounds__(256) void k_transform(const float* __restrict__ h,
                                                   const float* __restrict__ Wl,
                                                   const float* __restrict__ bl,
                                                   const float* __restrict__ Wr,
                                                   unsigned short* __restrict__ T,
                                                   float* __restrict__ S, int N) {
    int lane = threadIdx.x & 63;
    float wl[CH], wr[CH];
    const float4* Wl4 = (const float4*)(Wl + lane * CH);
    const float4* Wr4 = (const float4*)(Wr + lane * CH);
#pragma unroll
    for (int q = 0; q < CH / 4; ++q) {
        float4 a = Wl4[q];
        wl[4 * q] = a.x; wl[4 * q + 1] = a.y; wl[4 * q + 2] = a.z; wl[4 * q + 3] = a.w;
        float4 b = Wr4[q];
        wr[4 * q] = b.x; wr[4 * q + 1] = b.y; wr[4 * q + 2] = b.z; wr[4 * q + 3] = b.w;
    }
    float bias = bl[lane];

    int wid    = (blockIdx.x * blockDim.x + threadIdx.x) >> 6;
    int nwaves = (gridDim.x * blockDim.x) >> 6;
    for (int n = wid; n < N; n += nwaves) {
        float hv = h[n * CH + lane];
        float ol = 0.f, orr = 0.f;
#pragma unroll
        for (int c = 0; c < CH; ++c) {
            float hc = __uint_as_float(__builtin_amdgcn_readlane(__float_as_uint(hv), c));
            ol  += hc * wl[c];
            orr += hc * wr[c];
        }
        T[n * CH + lane] = f2bf(ol);
        S[n * CH + lane] = orr + bias;
    }
}

// ---------------- gather ----------------
// out[n][c] = relu?( S[n][c] + dinv[n] * sum_e T[col[e]][c] )
// one node per 32-lane half (2 nodes/wave): uint load = 2 bf16 channels/lane,
// unroll 4 edges -> 8 edge-rows in flight per wave; no cross-half combine.
__global__ __launch_bounds__(256) void k_gather(const unsigned short* __restrict__ T,
                                                const float* __restrict__ S,
                                                const int* __restrict__ rowp,
                                                const int* __restrict__ cnt,
                                                const float* __restrict__ dinv,
                                                const int* __restrict__ col,
                                                float* __restrict__ out,
                                                int relu, int N) {
    int li = threadIdx.x & 31;
    int n  = blockIdx.x * 8 + (threadIdx.x >> 5);
    if (n >= N) return;

    int start = rowp[n];
    int deg   = cnt[n];
    const int* cp = col + start;

    float a0 = 0.f, a1 = 0.f, b0 = 0.f, b1 = 0.f;
    float c0 = 0.f, c1 = 0.f, d0 = 0.f, d1 = 0.f;
    int e = 0;
    for (; e + 4 <= deg; e += 4) {
        int s0 = cp[e + 0];
        int s1 = cp[e + 1];
        int s2 = cp[e + 2];
        int s3 = cp[e + 3];
        unsigned u0 = *(const unsigned*)(T + (size_t)s0 * CH + 2 * li);
        unsigned u1 = *(const unsigned*)(T + (size_t)s1 * CH + 2 * li);
        unsigned u2 = *(const unsigned*)(T + (size_t)s2 * CH + 2 * li);
        unsigned u3 = *(const unsigned*)(T + (size_t)s3 * CH + 2 * li);
        a0 += bf2f((unsigned short)u0); a1 += bf2f((unsigned short)(u0 >> 16));
        b0 += bf2f((unsigned short)u1); b1 += bf2f((unsigned short)(u1 >> 16));
        c0 += bf2f((unsigned short)u2); c1 += bf2f((unsigned short)(u2 >> 16));
        d0 += bf2f((unsigned short)u3); d1 += bf2f((unsigned short)(u3 >> 16));
    }
    for (; e < deg; ++e) {
        int s = cp[e];
        unsigned u = *(const unsigned*)(T + (size_t)s * CH + 2 * li);
        a0 += bf2f((unsigned short)u); a1 += bf2f((unsigned short)(u >> 16));
    }
    float r0 = (a0 + b0) + (c0 + d0);
    float r1 = (a1 + b1) + (c1 + d1);

    float dv = dinv[n];
    float2 sv = *(const float2*)(S + (size_t)n * CH + 2 * li);
    float o0 = sv.x + r0 * dv;
    float o1 = sv.y + r1 * dv;
    if (relu) { o0 = fmaxf(o0, 0.f); o1 = fmaxf(o1, 0.f); }
    *(float2*)(out + (size_t)n * CH + 2 * li) = make_float2(o0, o1);
}

// ---------------- launch ----------------

extern "C" void kernel_launch(void* const* d_in, const int* in_sizes, int n_in,
                              void* d_out, int out_size, void* d_ws, size_t ws_size,
                              hipStream_t stream) {
    const float* x   = (const float*)d_in[0];
    const int*   ei  = (const int*)d_in[1];
    const int E = in_sizes[1] / 2;
    const int N = in_sizes[0] / CH;
    const int* src = ei;
    const int* dst = ei + E;

    const float* Wl[3] = { (const float*)d_in[2], (const float*)d_in[5], (const float*)d_in[8] };
    const float* bl[3] = { (const float*)d_in[3], (const float*)d_in[6], (const float*)d_in[9] };
    const float* Wr[3] = { (const float*)d_in[4], (const float*)d_in[7], (const float*)d_in[10] };

    char* ws = (char*)d_ws;
    size_t off = 0;
    auto take = [&](size_t bytes) { char* p = ws + off; off += (bytes + 255) & ~(size_t)255; return p; };
    int*            cnt    = (int*)           take((size_t)N * 4);
    int*            rowp   = (int*)           take((size_t)(N + 1) * 4);
    int*            cursor = (int*)           take((size_t)N * 4);
    float*          dinv   = (float*)         take((size_t)N * 4);
    int*            bsum   = (int*)           take(4096);
    int*            col    = (int*)           take((size_t)E * 4);
    unsigned short* T      = (unsigned short*)take((size_t)N * CH * 2);
    float*          S      = (float*)         take((size_t)N * CH * 4);
    float*          buf0   = (float*)         take((size_t)N * CH * 4);
    float*          outp   = (float*)d_out;

    hipMemsetAsync(cnt, 0, (size_t)N * 4, stream);

    int tb = 256;
    // 1024 blocks = 128 per range-group; groups stride the whole edge list in
    // lockstep (tid-interleaved) so edge lines are fetched once per XCD.
    k_hist<<<1024, tb, 0, stream>>>(dst, cnt, E, N);

    int nb = (N + 1023) / 1024;
    k_scanA<<<nb, 1024, 0, stream>>>(cnt, N, rowp, bsum);
    k_scanB<<<1, 1024, 0, stream>>>(bsum, nb);
    k_scanC<<<(N + tb - 1) / tb, tb, 0, stream>>>(rowp, cnt, bsum, cursor, dinv, N);
    k_fill<<<1024, tb, 0, stream>>>(src, dst, cursor, col, E, N);

    int gblocks = (N + 7) / 8;   // 8 nodes per 256-thread block (1 per 32-lane half)
    // layer 0
    k_transform<<<1024, 256, 0, stream>>>(x, Wl[0], bl[0], Wr[0], T, S, N);
    k_gather<<<gblocks, 256, 0, stream>>>(T, S, rowp, cnt, dinv, col, buf0, 1, N);
    // layer 1
    k_transform<<<1024, 256, 0, stream>>>(buf0, Wl[1], bl[1], Wr[1], T, S, N);
    k_gather<<<gblocks, 256, 0, stream>>>(T, S, rowp, cnt, dinv, col, buf0, 1, N);
    // layer 2
    k_transform<<<1024, 256, 0, stream>>>(buf0, Wl[2], bl[2], Wr[2], T, S, N);
    k_gather<<<gblocks, 256, 0, stream>>>(T, S, rowp, cnt, dinv, col, outp, 0, N);
}